// Round 2
// baseline (353.614 us; speedup 1.0000x reference)
//
#include <hip/hip_runtime.h>
#include <hip/hip_bf16.h>

#define B_    2
#define T_    2048
#define C_    2048
#define NH_   16
#define KVH_  4
#define HD_   128
#define QKV_  3072
#define M_    4096

typedef float  floatx4 __attribute__((ext_vector_type(4)));
typedef __bf16 bf16x8  __attribute__((ext_vector_type(8)));
typedef __bf16 bf16x4  __attribute__((ext_vector_type(4)));
typedef __bf16 bf16x2  __attribute__((ext_vector_type(2)));

typedef const __attribute__((address_space(1))) void* gas_t;
typedef __attribute__((address_space(3))) void*       las_t;
__device__ __forceinline__ void gl_lds16(const void* g, void* l) {
  __builtin_amdgcn_global_load_lds((gas_t)g, (las_t)l, 16, 0, 0);
}

// ---------------- fp32 -> bf16 conversion, all three tensors in one launch ----------
__global__ __launch_bounds__(256) void cvt3(const float* __restrict__ s0, __bf16* __restrict__ d0, int n0,
                                            const float* __restrict__ s1, __bf16* __restrict__ d1, int n1,
                                            const float* __restrict__ s2, __bf16* __restrict__ d2, int n2) {
  int i = blockIdx.x * blockDim.x + threadIdx.x;
  const float* s; __bf16* d;
  if (i < n0) { s = s0; d = d0; }
  else {
    i -= n0;
    if (i < n1) { s = s1; d = d1; }
    else { i -= n1; if (i >= n2) return; s = s2; d = d2; }
  }
  float4 f = ((const float4*)s)[i];
  bf16x4 o = { (__bf16)f.x, (__bf16)f.y, (__bf16)f.z, (__bf16)f.w };
  ((bf16x4*)d)[i] = o;
}

// ---------------- C = A[M][K] * B[N][K]^T, templated output dtype ----------------
// m97 structure, BK=64 staged as two BK=32 sub-buffers: 32 MFMAs per sync window.
template <typename OutT>
__global__ __launch_bounds__(256) void gemm_bt(const __bf16* __restrict__ A,
                                               const __bf16* __restrict__ Bm,
                                               OutT* __restrict__ Cc,
                                               int N, int K) {
  __shared__ __align__(16) __bf16 As[2][128 * 32];
  __shared__ __align__(16) __bf16 Bs[2][128 * 32];
  const int tid  = threadIdx.x;
  const int wid  = tid >> 6, lane = tid & 63, quad = lane >> 4, r16 = lane & 15;
  const int bm   = blockIdx.y * 128, bn = blockIdx.x * 128;
  const int wm   = (wid >> 1) * 64, wn = (wid & 1) * 64;
  const int srow = wid * 16 + (lane >> 2);
  const int scol = (lane & 3) * 8;
  const __bf16* aptr = A  + (size_t)(bm + srow) * K + scol;
  const __bf16* bptr = Bm + (size_t)(bn + srow) * K + scol;
  const size_t rowskip = (size_t)64 * K;

  floatx4 acc[4][4];
  #pragma unroll
  for (int i = 0; i < 4; i++)
    #pragma unroll
    for (int j = 0; j < 4; j++) acc[i][j] = (floatx4){0.f, 0.f, 0.f, 0.f};

  for (int k0 = 0; k0 < K; k0 += 64) {
    #pragma unroll
    for (int hf = 0; hf < 2; hf++) {
      gl_lds16(aptr + k0 + hf * 32,           &As[hf][wid * 512]);
      gl_lds16(aptr + rowskip + k0 + hf * 32, &As[hf][2048 + wid * 512]);
      gl_lds16(bptr + k0 + hf * 32,           &Bs[hf][wid * 512]);
      gl_lds16(bptr + rowskip + k0 + hf * 32, &Bs[hf][2048 + wid * 512]);
    }
    __syncthreads();

    #pragma unroll
    for (int hf = 0; hf < 2; hf++) {
      bf16x8 af[4], bfr[4];
      #pragma unroll
      for (int i = 0; i < 4; i++) af[i]  = *(const bf16x8*)&As[hf][(wm + i * 16 + r16) * 32 + quad * 8];
      #pragma unroll
      for (int j = 0; j < 4; j++) bfr[j] = *(const bf16x8*)&Bs[hf][(wn + j * 16 + r16) * 32 + quad * 8];
      #pragma unroll
      for (int i = 0; i < 4; i++)
        #pragma unroll
        for (int j = 0; j < 4; j++)
          acc[i][j] = __builtin_amdgcn_mfma_f32_16x16x32_bf16(af[i], bfr[j], acc[i][j], 0, 0, 0);
    }
    __syncthreads();
  }

  #pragma unroll
  for (int i = 0; i < 4; i++) {
    #pragma unroll
    for (int reg = 0; reg < 4; reg++) {
      int row = bm + wm + i * 16 + quad * 4 + reg;
      OutT* crow = Cc + (size_t)row * N + bn + wn;
      #pragma unroll
      for (int j = 0; j < 4; j++) crow[j * 16 + r16] = (OutT)acc[i][j][reg];
    }
  }
}

// ---------------- RoPE + RMSNorm (bf16 qkv input), one wave per (b,t) row ----------
__global__ __launch_bounds__(256) void rope_norm(const __bf16* __restrict__ qkv,
                                                 const float* __restrict__ qw,
                                                 const float* __restrict__ kw,
                                                 const float* __restrict__ fc,
                                                 const float* __restrict__ fs,
                                                 __bf16* __restrict__ qn,
                                                 __bf16* __restrict__ kn) {
  const int tid  = threadIdx.x;
  const int wid  = tid >> 6, lane = tid & 63;
  const int row  = blockIdx.x * 4 + wid;        // b*T + t
  const int b    = row >> 11, t = row & (T_ - 1);
  const float cs = fc[t * 64 + lane], sn = fs[t * 64 + lane];
  const __bf16* base = qkv + (size_t)row * QKV_;

  #pragma unroll 2
  for (int h = 0; h < NH_; h++) {
    bf16x2 ab = *(const bf16x2*)(base + h * HD_ + 2 * lane);
    float ax = (float)ab[0], ay = (float)ab[1];
    float oa = ax * cs - ay * sn;
    float ob = ax * sn + ay * cs;
    float ss = oa * oa + ob * ob;
    #pragma unroll
    for (int off = 32; off; off >>= 1) ss += __shfl_xor(ss, off);
    float rinv = rsqrtf(ss * (1.0f / HD_) + 1e-6f);
    bf16x2 o = { (__bf16)(oa * rinv * qw[2 * lane]), (__bf16)(ob * rinv * qw[2 * lane + 1]) };
    *(bf16x2*)&qn[(size_t)((b * NH_ + h) * T_ + t) * HD_ + 2 * lane] = o;
  }
  #pragma unroll 2
  for (int h = 0; h < KVH_; h++) {
    bf16x2 ab = *(const bf16x2*)(base + C_ + h * HD_ + 2 * lane);
    float ax = (float)ab[0], ay = (float)ab[1];
    float oa = ax * cs - ay * sn;
    float ob = ax * sn + ay * cs;
    float ss = oa * oa + ob * ob;
    #pragma unroll
    for (int off = 32; off; off >>= 1) ss += __shfl_xor(ss, off);
    float rinv = rsqrtf(ss * (1.0f / HD_) + 1e-6f);
    bf16x2 o = { (__bf16)(oa * rinv * kw[2 * lane]), (__bf16)(ob * rinv * kw[2 * lane + 1]) };
    *(bf16x2*)&kn[(size_t)((b * KVH_ + h) * T_ + t) * HD_ + 2 * lane] = o;
  }
}

// ---------------- V transpose: qkv bf16 [t][d] -> vT bf16 [d][t], 64x64 LDS tiles ----
__global__ __launch_bounds__(256) void vtrans(const __bf16* __restrict__ qkv,
                                              __bf16* __restrict__ vT) {
  __shared__ __bf16 L[64 * 68];
  const int tid = threadIdx.x;
  const int t0 = blockIdx.x * 64;
  const int d0 = blockIdx.y * 64;
  const int z  = blockIdx.z;            // b*KVH + hk
  const int b  = z >> 2, hk = z & 3;
  const int srcc = C_ + KVH_ * HD_ + hk * HD_ + d0;
  const int rr = tid >> 4, c4 = (tid & 15) * 4;
  #pragma unroll
  for (int i = 0; i < 4; i++) {
    int t = rr + i * 16;
    bf16x4 f = *(const bf16x4*)&qkv[(size_t)(b * T_ + t0 + t) * QKV_ + srcc + c4];
    *(bf16x4*)&L[t * 68 + c4] = f;
  }
  __syncthreads();
  const int dr = tid >> 3, tc8 = (tid & 7) * 8;
  #pragma unroll
  for (int i = 0; i < 2; i++) {
    int d = dr + i * 32;
    bf16x8 ov;
    #pragma unroll
    for (int j = 0; j < 8; j++) ov[j] = L[(tc8 + j) * 68 + d];
    *(bf16x8*)&vT[(size_t)(z * HD_ + d0 + d) * T_ + t0 + tc8] = ov;
  }
}

// ---------------- causal flash attention: 256 threads, 4 waves x 32 rows ----------
// LDS-bound analysis (round 1): every wave reads the whole 32KB Ks+Vs per K-tile,
// and the fragment read pattern (r16*64B + quad*16B) was 8-way bank-conflicted
// within 16-lane phases (9.2M conflict cycles/dispatch).  Fixes:
//  (a) XOR-swizzled 16B-chunk layout for Ks/Vs tiles: slot(kt,ds) = ds*16+(kt^2ds).
//      Both commit-write and fragment-read phases then hit each bank-group exactly
//      2x (free).  Both sides are register-staged so the swizzle is ours to choose.
//  (b) 32 Q-rows per wave (4 waves/block instead of 8x16): halves the number of
//      waves scanning Ks/Vs -> halves LDS fragment bandwidth.  K/V fragments are
//      loaded once and feed both row-groups' MFMAs.
// Grid stays 512 (2 blocks/CU): block x<256 takes heavy tile qt=15-p, x+256 the
// complementary light tile qt=p.
__device__ __forceinline__ int swz_w(int lane) {       // write slot for chunk c=lane
  return ((lane & 3) << 4) | ((lane >> 2) ^ ((lane & 3) << 1));
}
__device__ __forceinline__ int swz_r(int quad, int r16) { // read slot for (kt=r16, ds=quad)
  return (quad << 4) | (r16 ^ (quad << 1));
}

__device__ __forceinline__ void kv_prefetch16(const __bf16* kbase, const __bf16* vbase,
                                              int kt0, int wid, int lane,
                                              bf16x8 kreg[4], bf16x8 vreg[4]) {
  const int r4 = lane >> 2, c8 = (lane & 3) * 8;
  #pragma unroll
  for (int i = 0; i < 4; i++) {
    const int n = wid * 4 + i;   // K tile n: rows (n>>2)*16, cols (n&3)*32 ; V tile n: d-rows (n>>1)*16, kt-cols (n&1)*32
    kreg[i] = *(const bf16x8*)&kbase[(size_t)(kt0 + (n >> 2) * 16 + r4) * HD_ + (n & 3) * 32 + c8];
    vreg[i] = *(const bf16x8*)&vbase[(size_t)((n >> 1) * 16 + r4) * T_ + kt0 + (n & 1) * 32 + c8];
  }
}

__device__ __forceinline__ void kv_commit16(__bf16* Ks, __bf16* Vs, int wid, int lane,
                                            const bf16x8 kreg[4], const bf16x8 vreg[4]) {
  const int slot = swz_w(lane);
  #pragma unroll
  for (int i = 0; i < 4; i++) {
    *(bf16x8*)(Ks + (wid * 4 + i) * 512 + slot * 8) = kreg[i];
    *(bf16x8*)(Vs + (wid * 4 + i) * 512 + slot * 8) = vreg[i];
  }
}

__global__ __launch_bounds__(256, 2) void flash(const __bf16* __restrict__ q,
                                                const __bf16* __restrict__ k,
                                                const __bf16* __restrict__ vT,
                                                __bf16* __restrict__ y) {
  __shared__ __align__(16) __bf16 Ks[64 * 128];   // 16 swizzled tiles of [16kt][32d]
  __shared__ __align__(16) __bf16 Vs[128 * 64];   // 16 swizzled tiles of [16d][32kt]
  __shared__ __align__(16) __bf16 Ps[4][32 * 72]; // per-wave P scratch, +8 pad
  const int tid = threadIdx.x;
  const int wid = tid >> 6, lane = tid & 63, quad = lane >> 4, r16 = lane & 15;
  const int x   = blockIdx.x;
  const int p   = (x >> 5) & 7, hl = x & 31;
  const int qt  = (x < 256) ? (15 - p) : p;       // heavy half first; x and x+256 pair on one CU
  const int b = hl >> 4, h = hl & 15, hk = h >> 2;

  const __bf16* kbase = k  + (size_t)(b * KVH_ + hk) * T_ * HD_;
  const __bf16* vbase = vT + (size_t)(b * KVH_ + hk) * HD_ * T_;
  __bf16* Pw = Ps[wid];
  const float sc = 0.08838834764831845f;  // 1/sqrt(128)
  const float NEG = -__builtin_inff();
  bf16x8 ones;
  #pragma unroll
  for (int i = 0; i < 8; i++) ones[i] = (__bf16)1.0f;

  const int nt = 2 * (qt + 1);
  const int r0 = qt * 128 + wid * 32;   // this wave's 32 q-rows

  bf16x8 qf[2][4];
  #pragma unroll
  for (int rg = 0; rg < 2; rg++) {
    const __bf16* qrow = q + ((size_t)(b * NH_ + h) * T_ + r0 + rg * 16 + r16) * HD_;
    #pragma unroll
    for (int kb = 0; kb < 4; kb++) qf[rg][kb] = *(const bf16x8*)&qrow[kb * 32 + quad * 8];
  }

  floatx4 o[2][8], ol[2];
  float m_r[2][4];
  #pragma unroll
  for (int rg = 0; rg < 2; rg++) {
    ol[rg] = (floatx4){0.f, 0.f, 0.f, 0.f};
    #pragma unroll
    for (int j = 0; j < 8; j++) o[rg][j] = (floatx4){0.f, 0.f, 0.f, 0.f};
    #pragma unroll
    for (int reg = 0; reg < 4; reg++) m_r[rg][reg] = NEG;
  }

  bf16x8 kreg[4], vreg[4];
  kv_prefetch16(kbase, vbase, 0, wid, lane, kreg, vreg);

  #pragma unroll 1
  for (int it = 0; it < nt; ++it) {
    __syncthreads();                      // all waves done reading previous tile
    kv_commit16(Ks, Vs, wid, lane, kreg, vreg);
    __syncthreads();                      // tile it visible
    if (it + 1 < nt) kv_prefetch16(kbase, vbase, (it + 1) * 64, wid, lane, kreg, vreg);

    const int kt0 = it * 64;
    if (kt0 <= r0 + 31) {                 // wave-uniform causal skip (no barriers inside)
      floatx4 s[2][4];
      #pragma unroll
      for (int rg = 0; rg < 2; rg++)
        #pragma unroll
        for (int cb = 0; cb < 4; cb++) s[rg][cb] = (floatx4){0.f, 0.f, 0.f, 0.f};
      #pragma unroll
      for (int kb = 0; kb < 4; kb++)
        #pragma unroll
        for (int cb = 0; cb < 4; cb++) {
          bf16x8 kf = *(const bf16x8*)&Ks[(cb * 4 + kb) * 512 + swz_r(quad, r16) * 8];
          #pragma unroll
          for (int rg = 0; rg < 2; rg++)
            s[rg][cb] = __builtin_amdgcn_mfma_f32_16x16x32_bf16(qf[rg][kb], kf, s[rg][cb], 0, 0, 0);
        }

      float alpha[2][4];
      #pragma unroll
      for (int rg = 0; rg < 2; rg++) {
        const bool needmask = (kt0 + 63 > r0 + rg * 16);  // wave-uniform
        #pragma unroll
        for (int reg = 0; reg < 4; reg++) {
          const int rowq = r0 + rg * 16 + quad * 4 + reg;
          float v0 = s[rg][0][reg] * sc, v1 = s[rg][1][reg] * sc;
          float v2 = s[rg][2][reg] * sc, v3 = s[rg][3][reg] * sc;
          if (needmask) {
            if (kt0 +      r16 > rowq) v0 = NEG;
            if (kt0 + 16 + r16 > rowq) v1 = NEG;
            if (kt0 + 32 + r16 > rowq) v2 = NEG;
            if (kt0 + 48 + r16 > rowq) v3 = NEG;
          }
          float mx = fmaxf(fmaxf(v0, v1), fmaxf(v2, v3));
          #pragma unroll
          for (int off = 8; off; off >>= 1) mx = fmaxf(mx, __shfl_xor(mx, off));
          float mnew = fmaxf(m_r[rg][reg], mx);
          alpha[rg][reg] = __expf(m_r[rg][reg] - mnew);
          m_r[rg][reg] = mnew;
          const int prow = rg * 16 + quad * 4 + reg;
          Pw[prow * 72 +      r16] = (__bf16)__expf(v0 - mnew);
          Pw[prow * 72 + 16 + r16] = (__bf16)__expf(v1 - mnew);
          Pw[prow * 72 + 32 + r16] = (__bf16)__expf(v2 - mnew);
          Pw[prow * 72 + 48 + r16] = (__bf16)__expf(v3 - mnew);
        }
        #pragma unroll
        for (int reg = 0; reg < 4; reg++) {
          ol[rg][reg] *= alpha[rg][reg];
          #pragma unroll
          for (int j = 0; j < 8; j++) o[rg][j][reg] *= alpha[rg][reg];
        }
      }
      __asm__ volatile("" ::: "memory");  // wave-private P: writes before reads
      bf16x8 pf0[2], pf1[2];
      #pragma unroll
      for (int rg = 0; rg < 2; rg++) {
        pf0[rg] = *(const bf16x8*)&Pw[(rg * 16 + r16) * 72 + quad * 8];
        pf1[rg] = *(const bf16x8*)&Pw[(rg * 16 + r16) * 72 + 32 + quad * 8];
        ol[rg] = __builtin_amdgcn_mfma_f32_16x16x32_bf16(pf0[rg], ones, ol[rg], 0, 0, 0);
        ol[rg] = __builtin_amdgcn_mfma_f32_16x16x32_bf16(pf1[rg], ones, ol[rg], 0, 0, 0);
      }
      #pragma unroll
      for (int j = 0; j < 8; j++) {
        bf16x8 vf0 = *(const bf16x8*)&Vs[(j * 2 + 0) * 512 + swz_r(quad, r16) * 8];
        bf16x8 vf1 = *(const bf16x8*)&Vs[(j * 2 + 1) * 512 + swz_r(quad, r16) * 8];
        #pragma unroll
        for (int rg = 0; rg < 2; rg++) {
          o[rg][j] = __builtin_amdgcn_mfma_f32_16x16x32_bf16(pf0[rg], vf0, o[rg][j], 0, 0, 0);
          o[rg][j] = __builtin_amdgcn_mfma_f32_16x16x32_bf16(pf1[rg], vf1, o[rg][j], 0, 0, 0);
        }
      }
    }
  }

  #pragma unroll
  for (int rg = 0; rg < 2; rg++)
    #pragma unroll
    for (int reg = 0; reg < 4; reg++) {
      int trow = r0 + rg * 16 + quad * 4 + reg;
      float inv = 1.0f / ol[rg][reg];  // rowsum identical across lanes (ones-MFMA trick)
      __bf16* yr = y + ((size_t)(b * T_) + trow) * C_ + h * HD_;
      #pragma unroll
      for (int j = 0; j < 8; j++) yr[j * 16 + r16] = (__bf16)(o[rg][j][reg] * inv);
    }
}

extern "C" void kernel_launch(void* const* d_in, const int* in_sizes, int n_in,
                              void* d_out, int out_size, void* d_ws, size_t ws_size,
                              hipStream_t stream) {
  const float* x     = (const float*)d_in[0];
  const float* wqkv  = (const float*)d_in[1];
  const float* wproj = (const float*)d_in[2];
  const float* qw    = (const float*)d_in[3];
  const float* kw    = (const float*)d_in[4];
  const float* fc    = (const float*)d_in[5];
  const float* fs    = (const float*)d_in[6];
  float* out = (float*)d_out;

  char* w = (char*)d_ws;
  __bf16* xb     = (__bf16*)w; w += (size_t)M_ * C_ * 2;
  __bf16* wqkvb  = (__bf16*)w; w += (size_t)QKV_ * C_ * 2;
  __bf16* wprojb = (__bf16*)w; w += (size_t)C_ * C_ * 2;
  __bf16* qkv    = (__bf16*)w; w += (size_t)M_ * QKV_ * 2;
  __bf16* qn     = (__bf16*)w; w += (size_t)B_ * NH_ * T_ * HD_ * 2;
  __bf16* kn     = (__bf16*)w; w += (size_t)B_ * KVH_ * T_ * HD_ * 2;
  __bf16* vT     = (__bf16*)w; w += (size_t)B_ * KVH_ * T_ * HD_ * 2;
  __bf16* ybf    = (__bf16*)w; w += (size_t)M_ * C_ * 2;

  const int n0 = M_ * C_ / 4, n1 = QKV_ * C_ / 4, n2 = C_ * C_ / 4;
  cvt3<<<(n0 + n1 + n2 + 255) / 256, 256, 0, stream>>>(x, xb, n0, wqkv, wqkvb, n1, wproj, wprojb, n2);

  gemm_bt<__bf16><<<dim3(QKV_ / 128, M_ / 128), 256, 0, stream>>>(xb, wqkvb, qkv, QKV_, C_);
  rope_norm<<<M_ / 4, 256, 0, stream>>>(qkv, qw, kw, fc, fs, qn, kn);
  vtrans<<<dim3(T_ / 64, HD_ / 64, B_ * KVH_), 256, 0, stream>>>(qkv, vT);
  flash<<<dim3(512), 256, 0, stream>>>(qn, kn, vT, ybf);
  gemm_bt<float><<<dim3(C_ / 128, M_ / 128), 256, 0, stream>>>(ybf, wprojb, out, C_, C_);
}

// Round 3
// 325.932 us; speedup vs baseline: 1.0849x; 1.0849x over previous
//
#include <hip/hip_runtime.h>
#include <hip/hip_bf16.h>

#define B_    2
#define T_    2048
#define C_    2048
#define NH_   16
#define KVH_  4
#define HD_   128
#define QKV_  3072
#define M_    4096

typedef float  floatx4 __attribute__((ext_vector_type(4)));
typedef __bf16 bf16x8  __attribute__((ext_vector_type(8)));
typedef __bf16 bf16x4  __attribute__((ext_vector_type(4)));
typedef __bf16 bf16x2  __attribute__((ext_vector_type(2)));

typedef const __attribute__((address_space(1))) void* gas_t;
typedef __attribute__((address_space(3))) void*       las_t;
__device__ __forceinline__ void gl_lds16(const void* g, void* l) {
  __builtin_amdgcn_global_load_lds((gas_t)g, (las_t)l, 16, 0, 0);
}

// ---------------- fp32 -> bf16 conversion, all three tensors in one launch ----------
__global__ __launch_bounds__(256) void cvt3(const float* __restrict__ s0, __bf16* __restrict__ d0, int n0,
                                            const float* __restrict__ s1, __bf16* __restrict__ d1, int n1,
                                            const float* __restrict__ s2, __bf16* __restrict__ d2, int n2) {
  int i = blockIdx.x * blockDim.x + threadIdx.x;
  const float* s; __bf16* d;
  if (i < n0) { s = s0; d = d0; }
  else {
    i -= n0;
    if (i < n1) { s = s1; d = d1; }
    else { i -= n1; if (i >= n2) return; s = s2; d = d2; }
  }
  float4 f = ((const float4*)s)[i];
  bf16x4 o = { (__bf16)f.x, (__bf16)f.y, (__bf16)f.z, (__bf16)f.w };
  ((bf16x4*)d)[i] = o;
}

// ---------------- C = A[M][K] * B[N][K]^T, templated output dtype ----------------
// m97 structure, BK=64 staged as two BK=32 sub-buffers: 32 MFMAs per sync window.
template <typename OutT>
__global__ __launch_bounds__(256) void gemm_bt(const __bf16* __restrict__ A,
                                               const __bf16* __restrict__ Bm,
                                               OutT* __restrict__ Cc,
                                               int N, int K) {
  __shared__ __align__(16) __bf16 As[2][128 * 32];
  __shared__ __align__(16) __bf16 Bs[2][128 * 32];
  const int tid  = threadIdx.x;
  const int wid  = tid >> 6, lane = tid & 63, quad = lane >> 4, r16 = lane & 15;
  const int bm   = blockIdx.y * 128, bn = blockIdx.x * 128;
  const int wm   = (wid >> 1) * 64, wn = (wid & 1) * 64;
  const int srow = wid * 16 + (lane >> 2);
  const int scol = (lane & 3) * 8;
  const __bf16* aptr = A  + (size_t)(bm + srow) * K + scol;
  const __bf16* bptr = Bm + (size_t)(bn + srow) * K + scol;
  const size_t rowskip = (size_t)64 * K;

  floatx4 acc[4][4];
  #pragma unroll
  for (int i = 0; i < 4; i++)
    #pragma unroll
    for (int j = 0; j < 4; j++) acc[i][j] = (floatx4){0.f, 0.f, 0.f, 0.f};

  for (int k0 = 0; k0 < K; k0 += 64) {
    #pragma unroll
    for (int hf = 0; hf < 2; hf++) {
      gl_lds16(aptr + k0 + hf * 32,           &As[hf][wid * 512]);
      gl_lds16(aptr + rowskip + k0 + hf * 32, &As[hf][2048 + wid * 512]);
      gl_lds16(bptr + k0 + hf * 32,           &Bs[hf][wid * 512]);
      gl_lds16(bptr + rowskip + k0 + hf * 32, &Bs[hf][2048 + wid * 512]);
    }
    __syncthreads();

    #pragma unroll
    for (int hf = 0; hf < 2; hf++) {
      bf16x8 af[4], bfr[4];
      #pragma unroll
      for (int i = 0; i < 4; i++) af[i]  = *(const bf16x8*)&As[hf][(wm + i * 16 + r16) * 32 + quad * 8];
      #pragma unroll
      for (int j = 0; j < 4; j++) bfr[j] = *(const bf16x8*)&Bs[hf][(wn + j * 16 + r16) * 32 + quad * 8];
      #pragma unroll
      for (int i = 0; i < 4; i++)
        #pragma unroll
        for (int j = 0; j < 4; j++)
          acc[i][j] = __builtin_amdgcn_mfma_f32_16x16x32_bf16(af[i], bfr[j], acc[i][j], 0, 0, 0);
    }
    __syncthreads();
  }

  #pragma unroll
  for (int i = 0; i < 4; i++) {
    #pragma unroll
    for (int reg = 0; reg < 4; reg++) {
      int row = bm + wm + i * 16 + quad * 4 + reg;
      OutT* crow = Cc + (size_t)row * N + bn + wn;
      #pragma unroll
      for (int j = 0; j < 4; j++) crow[j * 16 + r16] = (OutT)acc[i][j][reg];
    }
  }
}

// ---------------- RoPE + RMSNorm (bf16 qkv input), one wave per (b,t) row ----------
__global__ __launch_bounds__(256) void rope_norm(const __bf16* __restrict__ qkv,
                                                 const float* __restrict__ qw,
                                                 const float* __restrict__ kw,
                                                 const float* __restrict__ fc,
                                                 const float* __restrict__ fs,
                                                 __bf16* __restrict__ qn,
                                                 __bf16* __restrict__ kn) {
  const int tid  = threadIdx.x;
  const int wid  = tid >> 6, lane = tid & 63;
  const int row  = blockIdx.x * 4 + wid;        // b*T + t
  const int b    = row >> 11, t = row & (T_ - 1);
  const float cs = fc[t * 64 + lane], sn = fs[t * 64 + lane];
  const __bf16* base = qkv + (size_t)row * QKV_;

  #pragma unroll 2
  for (int h = 0; h < NH_; h++) {
    bf16x2 ab = *(const bf16x2*)(base + h * HD_ + 2 * lane);
    float ax = (float)ab[0], ay = (float)ab[1];
    float oa = ax * cs - ay * sn;
    float ob = ax * sn + ay * cs;
    float ss = oa * oa + ob * ob;
    #pragma unroll
    for (int off = 32; off; off >>= 1) ss += __shfl_xor(ss, off);
    float rinv = rsqrtf(ss * (1.0f / HD_) + 1e-6f);
    bf16x2 o = { (__bf16)(oa * rinv * qw[2 * lane]), (__bf16)(ob * rinv * qw[2 * lane + 1]) };
    *(bf16x2*)&qn[(size_t)((b * NH_ + h) * T_ + t) * HD_ + 2 * lane] = o;
  }
  #pragma unroll 2
  for (int h = 0; h < KVH_; h++) {
    bf16x2 ab = *(const bf16x2*)(base + C_ + h * HD_ + 2 * lane);
    float ax = (float)ab[0], ay = (float)ab[1];
    float oa = ax * cs - ay * sn;
    float ob = ax * sn + ay * cs;
    float ss = oa * oa + ob * ob;
    #pragma unroll
    for (int off = 32; off; off >>= 1) ss += __shfl_xor(ss, off);
    float rinv = rsqrtf(ss * (1.0f / HD_) + 1e-6f);
    bf16x2 o = { (__bf16)(oa * rinv * kw[2 * lane]), (__bf16)(ob * rinv * kw[2 * lane + 1]) };
    *(bf16x2*)&kn[(size_t)((b * KVH_ + h) * T_ + t) * HD_ + 2 * lane] = o;
  }
}

// ---------------- V transpose: qkv bf16 [t][d] -> vT bf16 [d][t], 64x64 LDS tiles ----
__global__ __launch_bounds__(256) void vtrans(const __bf16* __restrict__ qkv,
                                              __bf16* __restrict__ vT) {
  __shared__ __bf16 L[64 * 68];
  const int tid = threadIdx.x;
  const int t0 = blockIdx.x * 64;
  const int d0 = blockIdx.y * 64;
  const int z  = blockIdx.z;            // b*KVH + hk
  const int b  = z >> 2, hk = z & 3;
  const int srcc = C_ + KVH_ * HD_ + hk * HD_ + d0;
  const int rr = tid >> 4, c4 = (tid & 15) * 4;
  #pragma unroll
  for (int i = 0; i < 4; i++) {
    int t = rr + i * 16;
    bf16x4 f = *(const bf16x4*)&qkv[(size_t)(b * T_ + t0 + t) * QKV_ + srcc + c4];
    *(bf16x4*)&L[t * 68 + c4] = f;
  }
  __syncthreads();
  const int dr = tid >> 3, tc8 = (tid & 7) * 8;
  #pragma unroll
  for (int i = 0; i < 2; i++) {
    int d = dr + i * 32;
    bf16x8 ov;
    #pragma unroll
    for (int j = 0; j < 8; j++) ov[j] = L[(tc8 + j) * 68 + d];
    *(bf16x8*)&vT[(size_t)(z * HD_ + d0 + d) * T_ + t0 + tc8] = ov;
  }
}

// ---------------- causal flash attention: 512 threads, 8 waves x 16 rows ----------
// Round-3 synthesis: round-1's 8-wave structure (parallelism won) + round-2's
// chunk-swizzled Ks/Vs layout (bank conflicts 9.2M -> 0.5M, proven correct).
// Layout: 16B chunk (kt,ds) of each [16][32] tile stored at slot ds*16+(kt^2ds).
//  - commit (64 lanes, chunk kt=lane>>2, ds=lane&3): slot = swz_w(lane); per
//    16-lane phase each bank is hit exactly 2x (free).
//  - fragment read (kt=r16, ds=quad): slot = swz_r(quad,r16); contiguous 256B
//    per phase, 2-way (free).  Both sides register-staged (rule #21 ok).
// Grid = 512 (2 blocks/CU): block x<256 takes heavy tile qt=15-p, x+256 the
// light tile qt=p; per-CU K-tile total stays 34.
__device__ __forceinline__ int swz_w(int lane) {       // write slot for chunk (kt=lane>>2, ds=lane&3)
  return ((lane & 3) << 4) | ((lane >> 2) ^ ((lane & 3) << 1));
}
__device__ __forceinline__ int swz_r(int quad, int r16) { // read slot for (kt=r16, ds=quad)
  return (quad << 4) | (r16 ^ (quad << 1));
}

__device__ __forceinline__ void kv_prefetch8(const __bf16* kbase, const __bf16* vbase,
                                             int kt0, int wid, int lane,
                                             bf16x8 kreg[2], bf16x8 vreg[2]) {
  const int r4 = lane >> 2, c8 = (lane & 3) * 8;
  #pragma unroll
  for (int i = 0; i < 2; i++) {
    const int n = wid * 2 + i;   // K tile: kt4 = n>>2 (16 kt rows), d4 = n&3 (32 d cols)
    kreg[i] = *(const bf16x8*)&kbase[(size_t)(kt0 + (n >> 2) * 16 + r4) * HD_ + (n & 3) * 32 + c8];
    vreg[i] = *(const bf16x8*)&vbase[(size_t)((n >> 1) * 16 + r4) * T_ + kt0 + (n & 1) * 32 + c8];
  }
}

__device__ __forceinline__ void kv_commit8(__bf16* Ks, __bf16* Vs, int wid, int lane,
                                           const bf16x8 kreg[2], const bf16x8 vreg[2]) {
  const int slot = swz_w(lane);
  #pragma unroll
  for (int i = 0; i < 2; i++) {
    *(bf16x8*)(Ks + (wid * 2 + i) * 512 + slot * 8) = kreg[i];
    *(bf16x8*)(Vs + (wid * 2 + i) * 512 + slot * 8) = vreg[i];
  }
}

__global__ __launch_bounds__(512, 4) void flash(const __bf16* __restrict__ q,
                                                const __bf16* __restrict__ k,
                                                const __bf16* __restrict__ vT,
                                                __bf16* __restrict__ y) {
  __shared__ __align__(16) __bf16 Ks[64 * 128];   // 16 swizzled tiles of [16kt][32d]
  __shared__ __align__(16) __bf16 Vs[128 * 64];   // 16 swizzled tiles of [16d][32kt]
  __shared__ __align__(16) __bf16 Ps[8][16 * 72]; // per-wave P scratch, +8 pad
  const int tid = threadIdx.x;
  const int wid = tid >> 6, lane = tid & 63, quad = lane >> 4, r16 = lane & 15;
  const int x   = blockIdx.x;
  const int p   = (x >> 5) & 7, hl = x & 31;
  const int qt  = (x < 256) ? (15 - p) : p;       // heavy half first; x and x+256 pair on one CU
  const int b = hl >> 4, h = hl & 15, hk = h >> 2;

  const __bf16* kbase = k  + (size_t)(b * KVH_ + hk) * T_ * HD_;
  const __bf16* vbase = vT + (size_t)(b * KVH_ + hk) * HD_ * T_;
  __bf16* Pw = Ps[wid];
  const float sc = 0.08838834764831845f;  // 1/sqrt(128)
  const float NEG = -__builtin_inff();
  bf16x8 ones;
  #pragma unroll
  for (int i = 0; i < 8; i++) ones[i] = (__bf16)1.0f;

  const int nt = 2 * (qt + 1);
  const int r0 = qt * 128 + wid * 16;   // this wave's 16 q-rows

  const __bf16* qrow = q + ((size_t)(b * NH_ + h) * T_ + r0 + r16) * HD_;
  bf16x8 qf[4];
  #pragma unroll
  for (int kb = 0; kb < 4; kb++) qf[kb] = *(const bf16x8*)&qrow[kb * 32 + quad * 8];

  floatx4 o[8], ol = (floatx4){0.f, 0.f, 0.f, 0.f};
  #pragma unroll
  for (int j = 0; j < 8; j++) o[j] = (floatx4){0.f, 0.f, 0.f, 0.f};
  float m_r[4] = {NEG, NEG, NEG, NEG};

  bf16x8 kreg[2], vreg[2];
  kv_prefetch8(kbase, vbase, 0, wid, lane, kreg, vreg);

  #pragma unroll 1
  for (int it = 0; it < nt; ++it) {
    __syncthreads();                      // all waves done reading previous tile
    kv_commit8(Ks, Vs, wid, lane, kreg, vreg);
    __syncthreads();                      // tile it visible
    if (it + 1 < nt) kv_prefetch8(kbase, vbase, (it + 1) * 64, wid, lane, kreg, vreg);

    const int kt0 = it * 64;
    if (kt0 <= r0 + 15) {                 // wave-uniform causal skip (no barriers inside)
      floatx4 s[4];
      #pragma unroll
      for (int cb = 0; cb < 4; cb++) s[cb] = (floatx4){0.f, 0.f, 0.f, 0.f};
      #pragma unroll
      for (int kb = 0; kb < 4; kb++)
        #pragma unroll
        for (int cb = 0; cb < 4; cb++) {
          bf16x8 kf = *(const bf16x8*)&Ks[(cb * 4 + kb) * 512 + swz_r(quad, r16) * 8];
          s[cb] = __builtin_amdgcn_mfma_f32_16x16x32_bf16(qf[kb], kf, s[cb], 0, 0, 0);
        }

      const bool needmask = (kt0 + 63 > r0);  // wave-uniform
      float alpha[4];
      #pragma unroll
      for (int reg = 0; reg < 4; reg++) {
        const int rowq = r0 + quad * 4 + reg;
        float v0 = s[0][reg] * sc, v1 = s[1][reg] * sc;
        float v2 = s[2][reg] * sc, v3 = s[3][reg] * sc;
        if (needmask) {
          if (kt0 +      r16 > rowq) v0 = NEG;
          if (kt0 + 16 + r16 > rowq) v1 = NEG;
          if (kt0 + 32 + r16 > rowq) v2 = NEG;
          if (kt0 + 48 + r16 > rowq) v3 = NEG;
        }
        float mx = fmaxf(fmaxf(v0, v1), fmaxf(v2, v3));
        #pragma unroll
        for (int off = 8; off; off >>= 1) mx = fmaxf(mx, __shfl_xor(mx, off));
        float mnew = fmaxf(m_r[reg], mx);
        alpha[reg] = __expf(m_r[reg] - mnew);
        m_r[reg] = mnew;
        Pw[(quad * 4 + reg) * 72 +      r16] = (__bf16)__expf(v0 - mnew);
        Pw[(quad * 4 + reg) * 72 + 16 + r16] = (__bf16)__expf(v1 - mnew);
        Pw[(quad * 4 + reg) * 72 + 32 + r16] = (__bf16)__expf(v2 - mnew);
        Pw[(quad * 4 + reg) * 72 + 48 + r16] = (__bf16)__expf(v3 - mnew);
      }
      #pragma unroll
      for (int reg = 0; reg < 4; reg++) {
        ol[reg] *= alpha[reg];
        #pragma unroll
        for (int j = 0; j < 8; j++) o[j][reg] *= alpha[reg];
      }
      __asm__ volatile("" ::: "memory");  // wave-private P: writes before reads
      bf16x8 pf0 = *(const bf16x8*)&Pw[r16 * 72 + quad * 8];
      bf16x8 pf1 = *(const bf16x8*)&Pw[r16 * 72 + 32 + quad * 8];
      ol = __builtin_amdgcn_mfma_f32_16x16x32_bf16(pf0, ones, ol, 0, 0, 0);
      ol = __builtin_amdgcn_mfma_f32_16x16x32_bf16(pf1, ones, ol, 0, 0, 0);
      #pragma unroll
      for (int j = 0; j < 8; j++) {
        bf16x8 vf0 = *(const bf16x8*)&Vs[(j * 2 + 0) * 512 + swz_r(quad, r16) * 8];
        bf16x8 vf1 = *(const bf16x8*)&Vs[(j * 2 + 1) * 512 + swz_r(quad, r16) * 8];
        o[j] = __builtin_amdgcn_mfma_f32_16x16x32_bf16(pf0, vf0, o[j], 0, 0, 0);
        o[j] = __builtin_amdgcn_mfma_f32_16x16x32_bf16(pf1, vf1, o[j], 0, 0, 0);
      }
    }
  }

  #pragma unroll
  for (int reg = 0; reg < 4; reg++) {
    int trow = r0 + quad * 4 + reg;
    float inv = 1.0f / ol[reg];  // rowsum identical across lanes (ones-MFMA trick)
    __bf16* yr = y + ((size_t)(b * T_) + trow) * C_ + h * HD_;
    #pragma unroll
    for (int j = 0; j < 8; j++) yr[j * 16 + r16] = (__bf16)(o[j][reg] * inv);
  }
}

extern "C" void kernel_launch(void* const* d_in, const int* in_sizes, int n_in,
                              void* d_out, int out_size, void* d_ws, size_t ws_size,
                              hipStream_t stream) {
  const float* x     = (const float*)d_in[0];
  const float* wqkv  = (const float*)d_in[1];
  const float* wproj = (const float*)d_in[2];
  const float* qw    = (const float*)d_in[3];
  const float* kw    = (const float*)d_in[4];
  const float* fc    = (const float*)d_in[5];
  const float* fs    = (const float*)d_in[6];
  float* out = (float*)d_out;

  char* w = (char*)d_ws;
  __bf16* xb     = (__bf16*)w; w += (size_t)M_ * C_ * 2;
  __bf16* wqkvb  = (__bf16*)w; w += (size_t)QKV_ * C_ * 2;
  __bf16* wprojb = (__bf16*)w; w += (size_t)C_ * C_ * 2;
  __bf16* qkv    = (__bf16*)w; w += (size_t)M_ * QKV_ * 2;
  __bf16* qn     = (__bf16*)w; w += (size_t)B_ * NH_ * T_ * HD_ * 2;
  __bf16* kn     = (__bf16*)w; w += (size_t)B_ * KVH_ * T_ * HD_ * 2;
  __bf16* vT     = (__bf16*)w; w += (size_t)B_ * KVH_ * T_ * HD_ * 2;
  __bf16* ybf    = (__bf16*)w; w += (size_t)M_ * C_ * 2;

  const int n0 = M_ * C_ / 4, n1 = QKV_ * C_ / 4, n2 = C_ * C_ / 4;
  cvt3<<<(n0 + n1 + n2 + 255) / 256, 256, 0, stream>>>(x, xb, n0, wqkv, wqkvb, n1, wproj, wprojb, n2);

  gemm_bt<__bf16><<<dim3(QKV_ / 128, M_ / 128), 256, 0, stream>>>(xb, wqkvb, qkv, QKV_, C_);
  rope_norm<<<M_ / 4, 256, 0, stream>>>(qkv, qw, kw, fc, fs, qn, kn);
  vtrans<<<dim3(T_ / 64, HD_ / 64, B_ * KVH_), 256, 0, stream>>>(qkv, vT);
  flash<<<dim3(512), 512, 0, stream>>>(qn, kn, vT, ybf);
  gemm_bt<float><<<dim3(C_ / 128, M_ / 128), 256, 0, stream>>>(ybf, wprojb, out, C_, C_);
}

// Round 4
// 322.472 us; speedup vs baseline: 1.0966x; 1.0107x over previous
//
#include <hip/hip_runtime.h>
#include <hip/hip_bf16.h>

#define B_    2
#define T_    2048
#define C_    2048
#define NH_   16
#define KVH_  4
#define HD_   128
#define QKV_  3072
#define M_    4096

typedef float  floatx4 __attribute__((ext_vector_type(4)));
typedef __bf16 bf16x8  __attribute__((ext_vector_type(8)));
typedef __bf16 bf16x4  __attribute__((ext_vector_type(4)));
typedef __bf16 bf16x2  __attribute__((ext_vector_type(2)));

typedef const __attribute__((address_space(1))) void* gas_t;
typedef __attribute__((address_space(3))) void*       las_t;
__device__ __forceinline__ void gl_lds16(const void* g, void* l) {
  __builtin_amdgcn_global_load_lds((gas_t)g, (las_t)l, 16, 0, 0);
}

// ---------------- fp32 -> bf16 conversion, all three tensors in one launch ----------
__global__ __launch_bounds__(256) void cvt3(const float* __restrict__ s0, __bf16* __restrict__ d0, int n0,
                                            const float* __restrict__ s1, __bf16* __restrict__ d1, int n1,
                                            const float* __restrict__ s2, __bf16* __restrict__ d2, int n2) {
  int i = blockIdx.x * blockDim.x + threadIdx.x;
  const float* s; __bf16* d;
  if (i < n0) { s = s0; d = d0; }
  else {
    i -= n0;
    if (i < n1) { s = s1; d = d1; }
    else { i -= n1; if (i >= n2) return; s = s2; d = d2; }
  }
  float4 f = ((const float4*)s)[i];
  bf16x4 o = { (__bf16)f.x, (__bf16)f.y, (__bf16)f.z, (__bf16)f.w };
  ((bf16x4*)d)[i] = o;
}

// ---------------- C = A[M][K] * B[N][K]^T, templated output dtype ----------------
// m97 structure, BK=64 staged as two BK=32 sub-buffers: 32 MFMAs per sync window.
template <typename OutT>
__global__ __launch_bounds__(256) void gemm_bt(const __bf16* __restrict__ A,
                                               const __bf16* __restrict__ Bm,
                                               OutT* __restrict__ Cc,
                                               int N, int K) {
  __shared__ __align__(16) __bf16 As[2][128 * 32];
  __shared__ __align__(16) __bf16 Bs[2][128 * 32];
  const int tid  = threadIdx.x;
  const int wid  = tid >> 6, lane = tid & 63, quad = lane >> 4, r16 = lane & 15;
  const int bm   = blockIdx.y * 128, bn = blockIdx.x * 128;
  const int wm   = (wid >> 1) * 64, wn = (wid & 1) * 64;
  const int srow = wid * 16 + (lane >> 2);
  const int scol = (lane & 3) * 8;
  const __bf16* aptr = A  + (size_t)(bm + srow) * K + scol;
  const __bf16* bptr = Bm + (size_t)(bn + srow) * K + scol;
  const size_t rowskip = (size_t)64 * K;

  floatx4 acc[4][4];
  #pragma unroll
  for (int i = 0; i < 4; i++)
    #pragma unroll
    for (int j = 0; j < 4; j++) acc[i][j] = (floatx4){0.f, 0.f, 0.f, 0.f};

  for (int k0 = 0; k0 < K; k0 += 64) {
    #pragma unroll
    for (int hf = 0; hf < 2; hf++) {
      gl_lds16(aptr + k0 + hf * 32,           &As[hf][wid * 512]);
      gl_lds16(aptr + rowskip + k0 + hf * 32, &As[hf][2048 + wid * 512]);
      gl_lds16(bptr + k0 + hf * 32,           &Bs[hf][wid * 512]);
      gl_lds16(bptr + rowskip + k0 + hf * 32, &Bs[hf][2048 + wid * 512]);
    }
    __syncthreads();

    #pragma unroll
    for (int hf = 0; hf < 2; hf++) {
      bf16x8 af[4], bfr[4];
      #pragma unroll
      for (int i = 0; i < 4; i++) af[i]  = *(const bf16x8*)&As[hf][(wm + i * 16 + r16) * 32 + quad * 8];
      #pragma unroll
      for (int j = 0; j < 4; j++) bfr[j] = *(const bf16x8*)&Bs[hf][(wn + j * 16 + r16) * 32 + quad * 8];
      #pragma unroll
      for (int i = 0; i < 4; i++)
        #pragma unroll
        for (int j = 0; j < 4; j++)
          acc[i][j] = __builtin_amdgcn_mfma_f32_16x16x32_bf16(af[i], bfr[j], acc[i][j], 0, 0, 0);
    }
    __syncthreads();
  }

  #pragma unroll
  for (int i = 0; i < 4; i++) {
    #pragma unroll
    for (int reg = 0; reg < 4; reg++) {
      int row = bm + wm + i * 16 + quad * 4 + reg;
      OutT* crow = Cc + (size_t)row * N + bn + wn;
      #pragma unroll
      for (int j = 0; j < 4; j++) crow[j * 16 + r16] = (OutT)acc[i][j][reg];
    }
  }
}

// ---------------- RoPE + RMSNorm (bf16 qkv input), one wave per (b,t) row ----------
__global__ __launch_bounds__(256) void rope_norm(const __bf16* __restrict__ qkv,
                                                 const float* __restrict__ qw,
                                                 const float* __restrict__ kw,
                                                 const float* __restrict__ fc,
                                                 const float* __restrict__ fs,
                                                 __bf16* __restrict__ qn,
                                                 __bf16* __restrict__ kn) {
  const int tid  = threadIdx.x;
  const int wid  = tid >> 6, lane = tid & 63;
  const int row  = blockIdx.x * 4 + wid;        // b*T + t
  const int b    = row >> 11, t = row & (T_ - 1);
  const float cs = fc[t * 64 + lane], sn = fs[t * 64 + lane];
  const __bf16* base = qkv + (size_t)row * QKV_;

  #pragma unroll 2
  for (int h = 0; h < NH_; h++) {
    bf16x2 ab = *(const bf16x2*)(base + h * HD_ + 2 * lane);
    float ax = (float)ab[0], ay = (float)ab[1];
    float oa = ax * cs - ay * sn;
    float ob = ax * sn + ay * cs;
    float ss = oa * oa + ob * ob;
    #pragma unroll
    for (int off = 32; off; off >>= 1) ss += __shfl_xor(ss, off);
    float rinv = rsqrtf(ss * (1.0f / HD_) + 1e-6f);
    bf16x2 o = { (__bf16)(oa * rinv * qw[2 * lane]), (__bf16)(ob * rinv * qw[2 * lane + 1]) };
    *(bf16x2*)&qn[(size_t)((b * NH_ + h) * T_ + t) * HD_ + 2 * lane] = o;
  }
  #pragma unroll 2
  for (int h = 0; h < KVH_; h++) {
    bf16x2 ab = *(const bf16x2*)(base + C_ + h * HD_ + 2 * lane);
    float ax = (float)ab[0], ay = (float)ab[1];
    float oa = ax * cs - ay * sn;
    float ob = ax * sn + ay * cs;
    float ss = oa * oa + ob * ob;
    #pragma unroll
    for (int off = 32; off; off >>= 1) ss += __shfl_xor(ss, off);
    float rinv = rsqrtf(ss * (1.0f / HD_) + 1e-6f);
    bf16x2 o = { (__bf16)(oa * rinv * kw[2 * lane]), (__bf16)(ob * rinv * kw[2 * lane + 1]) };
    *(bf16x2*)&kn[(size_t)((b * KVH_ + h) * T_ + t) * HD_ + 2 * lane] = o;
  }
}

// ---------------- V transpose: qkv bf16 [t][d] -> vT bf16 [d][t], 64x64 LDS tiles ----
__global__ __launch_bounds__(256) void vtrans(const __bf16* __restrict__ qkv,
                                              __bf16* __restrict__ vT) {
  __shared__ __bf16 L[64 * 68];
  const int tid = threadIdx.x;
  const int t0 = blockIdx.x * 64;
  const int d0 = blockIdx.y * 64;
  const int z  = blockIdx.z;            // b*KVH + hk
  const int b  = z >> 2, hk = z & 3;
  const int srcc = C_ + KVH_ * HD_ + hk * HD_ + d0;
  const int rr = tid >> 4, c4 = (tid & 15) * 4;
  #pragma unroll
  for (int i = 0; i < 4; i++) {
    int t = rr + i * 16;
    bf16x4 f = *(const bf16x4*)&qkv[(size_t)(b * T_ + t0 + t) * QKV_ + srcc + c4];
    *(bf16x4*)&L[t * 68 + c4] = f;
  }
  __syncthreads();
  const int dr = tid >> 3, tc8 = (tid & 7) * 8;
  #pragma unroll
  for (int i = 0; i < 2; i++) {
    int d = dr + i * 32;
    bf16x8 ov;
    #pragma unroll
    for (int j = 0; j < 8; j++) ov[j] = L[(tc8 + j) * 68 + d];
    *(bf16x8*)&vT[(size_t)(z * HD_ + d0 + d) * T_ + t0 + tc8] = ov;
  }
}

// ---------------- causal flash attention: 512 threads, 8 waves x 16 rows ----------
// Round-4: flash was barrier/serial-chain bound (~6100 cy per K-tile vs ~2000 of
// pipe work; MfmaUtil 17, VALU 36, HBM 6%).  Changes:
//  (1) Double-buffered Ks/Vs -> ONE barrier per K-tile (was 2).  commit(t+1) goes
//      to buf[(t+1)&1]; its previous readers (tile t-1) were sealed by the
//      end-of-iter barrier; compute(t) reads buf[t&1] made visible by the same
//      barrier.  (2) P scratch chunked to 2x32 cols (Pw[16][48], stride 48 = 24
//      banks -> the 4 write rows partition all 32 banks: conflict-free) so total
//      LDS = 64KB + 12KB = 77.8KB keeps 2 blocks/CU.  (3) T5 setprio around MFMA
//      clusters (m191 +4-7%).  (4) T13 defer-max: skip alpha-rescale when
//      __all(growth <= 8) (m214v23 +5%).
// Grid = 512 (2 blocks/CU): block x<256 takes heavy tile qt=15-p, x+256 the
// light tile qt=p; per-CU K-tile total stays 34.
__device__ __forceinline__ int swz_w(int lane) {       // write slot for chunk (kt=lane>>2, ds=lane&3)
  return ((lane & 3) << 4) | ((lane >> 2) ^ ((lane & 3) << 1));
}
__device__ __forceinline__ int swz_r(int quad, int r16) { // read slot for (kt=r16, ds=quad)
  return (quad << 4) | (r16 ^ (quad << 1));
}

__device__ __forceinline__ void kv_prefetch8(const __bf16* kbase, const __bf16* vbase,
                                             int kt0, int wid, int lane,
                                             bf16x8 kreg[2], bf16x8 vreg[2]) {
  const int r4 = lane >> 2, c8 = (lane & 3) * 8;
  #pragma unroll
  for (int i = 0; i < 2; i++) {
    const int n = wid * 2 + i;   // K tile: kt4 = n>>2 (16 kt rows), d4 = n&3 (32 d cols)
    kreg[i] = *(const bf16x8*)&kbase[(size_t)(kt0 + (n >> 2) * 16 + r4) * HD_ + (n & 3) * 32 + c8];
    vreg[i] = *(const bf16x8*)&vbase[(size_t)((n >> 1) * 16 + r4) * T_ + kt0 + (n & 1) * 32 + c8];
  }
}

__device__ __forceinline__ void kv_commit8(__bf16* Ks, __bf16* Vs, int wid, int lane,
                                           const bf16x8 kreg[2], const bf16x8 vreg[2]) {
  const int slot = swz_w(lane);
  #pragma unroll
  for (int i = 0; i < 2; i++) {
    *(bf16x8*)(Ks + (wid * 2 + i) * 512 + slot * 8) = kreg[i];
    *(bf16x8*)(Vs + (wid * 2 + i) * 512 + slot * 8) = vreg[i];
  }
}

__global__ __launch_bounds__(512, 4) void flash(const __bf16* __restrict__ q,
                                                const __bf16* __restrict__ k,
                                                const __bf16* __restrict__ vT,
                                                __bf16* __restrict__ y) {
  __shared__ __align__(16) __bf16 Ks[2][64 * 128];  // dbuf x 16 swizzled tiles [16kt][32d]
  __shared__ __align__(16) __bf16 Vs[2][64 * 128];  // dbuf x 16 swizzled tiles [16d][32kt]
  __shared__ __align__(16) __bf16 Ps[8][16 * 48];   // per-wave P chunk scratch (32 cols)
  const int tid = threadIdx.x;
  const int wid = tid >> 6, lane = tid & 63, quad = lane >> 4, r16 = lane & 15;
  const int x   = blockIdx.x;
  const int p   = (x >> 5) & 7, hl = x & 31;
  const int qt  = (x < 256) ? (15 - p) : p;       // heavy half first; x and x+256 pair on one CU
  const int b = hl >> 4, h = hl & 15, hk = h >> 2;

  const __bf16* kbase = k  + (size_t)(b * KVH_ + hk) * T_ * HD_;
  const __bf16* vbase = vT + (size_t)(b * KVH_ + hk) * HD_ * T_;
  __bf16* Pw = Ps[wid];
  const float sc = 0.08838834764831845f;  // 1/sqrt(128)
  const float NEG = -__builtin_inff();
  bf16x8 ones;
  #pragma unroll
  for (int i = 0; i < 8; i++) ones[i] = (__bf16)1.0f;

  const int nt = 2 * (qt + 1);
  const int r0 = qt * 128 + wid * 16;   // this wave's 16 q-rows

  const __bf16* qrow = q + ((size_t)(b * NH_ + h) * T_ + r0 + r16) * HD_;
  bf16x8 qf[4];
  #pragma unroll
  for (int kb = 0; kb < 4; kb++) qf[kb] = *(const bf16x8*)&qrow[kb * 32 + quad * 8];

  floatx4 o[8], ol = (floatx4){0.f, 0.f, 0.f, 0.f};
  #pragma unroll
  for (int j = 0; j < 8; j++) o[j] = (floatx4){0.f, 0.f, 0.f, 0.f};
  float m_r[4] = {NEG, NEG, NEG, NEG};

  bf16x8 kreg[2], vreg[2];
  kv_prefetch8(kbase, vbase, 0, wid, lane, kreg, vreg);
  kv_commit8(&Ks[0][0], &Vs[0][0], wid, lane, kreg, vreg);
  if (nt > 1) kv_prefetch8(kbase, vbase, 64, wid, lane, kreg, vreg);
  __syncthreads();                        // tile 0 visible

  #pragma unroll 1
  for (int it = 0; it < nt; ++it) {
    if (it + 1 < nt) {
      // buf[(it+1)&1]'s previous readers (tile it-1) finished at the barrier
      // ending iter it-1, so this commit is race-free.
      kv_commit8(&Ks[(it + 1) & 1][0], &Vs[(it + 1) & 1][0], wid, lane, kreg, vreg);
      if (it + 2 < nt) kv_prefetch8(kbase, vbase, (it + 2) * 64, wid, lane, kreg, vreg);
    }

    const int kt0 = it * 64;
    const __bf16* Kb = &Ks[it & 1][0];
    const __bf16* Vb = &Vs[it & 1][0];
    if (kt0 <= r0 + 15) {                 // wave-uniform causal skip (no barriers inside)
      floatx4 s[4];
      #pragma unroll
      for (int cb = 0; cb < 4; cb++) s[cb] = (floatx4){0.f, 0.f, 0.f, 0.f};
      __builtin_amdgcn_s_setprio(1);
      #pragma unroll
      for (int kb = 0; kb < 4; kb++)
        #pragma unroll
        for (int cb = 0; cb < 4; cb++) {
          bf16x8 kf = *(const bf16x8*)&Kb[(cb * 4 + kb) * 512 + swz_r(quad, r16) * 8];
          s[cb] = __builtin_amdgcn_mfma_f32_16x16x32_bf16(qf[kb], kf, s[cb], 0, 0, 0);
        }
      __builtin_amdgcn_s_setprio(0);

      // scale + causal mask in place
      const bool needmask = (kt0 + 63 > r0);  // wave-uniform
      #pragma unroll
      for (int reg = 0; reg < 4; reg++) {
        const int rowq = r0 + quad * 4 + reg;
        s[0][reg] *= sc; s[1][reg] *= sc; s[2][reg] *= sc; s[3][reg] *= sc;
        if (needmask) {
          if (kt0 +      r16 > rowq) s[0][reg] = NEG;
          if (kt0 + 16 + r16 > rowq) s[1][reg] = NEG;
          if (kt0 + 32 + r16 > rowq) s[2][reg] = NEG;
          if (kt0 + 48 + r16 > rowq) s[3][reg] = NEG;
        }
      }
      // per-row max + running-max bookkeeping
      float mx[4], mnew[4];
      #pragma unroll
      for (int reg = 0; reg < 4; reg++) {
        float m0 = fmaxf(fmaxf(s[0][reg], s[1][reg]), fmaxf(s[2][reg], s[3][reg]));
        #pragma unroll
        for (int off = 8; off; off >>= 1) m0 = fmaxf(m0, __shfl_xor(m0, off));
        mx[reg] = m0;
        mnew[reg] = fmaxf(m_r[reg], m0);
      }
      // T13 defer-max: if no row grew its max by >8, keep old m (P bounded by e^8)
      float growth = fmaxf(fmaxf(mx[0] - m_r[0], mx[1] - m_r[1]),
                           fmaxf(mx[2] - m_r[2], mx[3] - m_r[3]));
      if (!__all(growth <= 8.0f)) {
        #pragma unroll
        for (int reg = 0; reg < 4; reg++) {
          float a = __expf(m_r[reg] - mnew[reg]);
          m_r[reg] = mnew[reg];
          ol[reg] *= a;
          #pragma unroll
          for (int j = 0; j < 8; j++) o[j][reg] *= a;
        }
      }
      // two 32-col chunks: exp -> Pw -> P-frag -> rowsum + PV MFMAs
      #pragma unroll
      for (int c = 0; c < 2; c++) {
        #pragma unroll
        for (int reg = 0; reg < 4; reg++) {
          const int prow = quad * 4 + reg;
          Pw[prow * 48 +      r16] = (__bf16)__expf(s[2 * c    ][reg] - m_r[reg]);
          Pw[prow * 48 + 16 + r16] = (__bf16)__expf(s[2 * c + 1][reg] - m_r[reg]);
        }
        __asm__ volatile("" ::: "memory");  // wave-private P: writes before reads
        bf16x8 pf = *(const bf16x8*)&Pw[r16 * 48 + quad * 8];
        __builtin_amdgcn_s_setprio(1);
        ol = __builtin_amdgcn_mfma_f32_16x16x32_bf16(pf, ones, ol, 0, 0, 0);
        #pragma unroll
        for (int j = 0; j < 8; j++) {
          bf16x8 vf = *(const bf16x8*)&Vb[(j * 2 + c) * 512 + swz_r(quad, r16) * 8];
          o[j] = __builtin_amdgcn_mfma_f32_16x16x32_bf16(pf, vf, o[j], 0, 0, 0);
        }
        __builtin_amdgcn_s_setprio(0);
        __asm__ volatile("" ::: "memory");  // keep chunk1 writes after chunk0 reads
      }
    }
    __syncthreads();                      // seals tile it reads; publishes tile it+1
  }

  #pragma unroll
  for (int reg = 0; reg < 4; reg++) {
    int trow = r0 + quad * 4 + reg;
    float inv = 1.0f / ol[reg];  // rowsum identical across lanes (ones-MFMA trick)
    __bf16* yr = y + ((size_t)(b * T_) + trow) * C_ + h * HD_;
    #pragma unroll
    for (int j = 0; j < 8; j++) yr[j * 16 + r16] = (__bf16)(o[j][reg] * inv);
  }
}

extern "C" void kernel_launch(void* const* d_in, const int* in_sizes, int n_in,
                              void* d_out, int out_size, void* d_ws, size_t ws_size,
                              hipStream_t stream) {
  const float* x     = (const float*)d_in[0];
  const float* wqkv  = (const float*)d_in[1];
  const float* wproj = (const float*)d_in[2];
  const float* qw    = (const float*)d_in[3];
  const float* kw    = (const float*)d_in[4];
  const float* fc    = (const float*)d_in[5];
  const float* fs    = (const float*)d_in[6];
  float* out = (float*)d_out;

  char* w = (char*)d_ws;
  __bf16* xb     = (__bf16*)w; w += (size_t)M_ * C_ * 2;
  __bf16* wqkvb  = (__bf16*)w; w += (size_t)QKV_ * C_ * 2;
  __bf16* wprojb = (__bf16*)w; w += (size_t)C_ * C_ * 2;
  __bf16* qkv    = (__bf16*)w; w += (size_t)M_ * QKV_ * 2;
  __bf16* qn     = (__bf16*)w; w += (size_t)B_ * NH_ * T_ * HD_ * 2;
  __bf16* kn     = (__bf16*)w; w += (size_t)B_ * KVH_ * T_ * HD_ * 2;
  __bf16* vT     = (__bf16*)w; w += (size_t)B_ * KVH_ * T_ * HD_ * 2;
  __bf16* ybf    = (__bf16*)w; w += (size_t)M_ * C_ * 2;

  const int n0 = M_ * C_ / 4, n1 = QKV_ * C_ / 4, n2 = C_ * C_ / 4;
  cvt3<<<(n0 + n1 + n2 + 255) / 256, 256, 0, stream>>>(x, xb, n0, wqkv, wqkvb, n1, wproj, wprojb, n2);

  gemm_bt<__bf16><<<dim3(QKV_ / 128, M_ / 128), 256, 0, stream>>>(xb, wqkvb, qkv, QKV_, C_);
  rope_norm<<<M_ / 4, 256, 0, stream>>>(qkv, qw, kw, fc, fs, qn, kn);
  vtrans<<<dim3(T_ / 64, HD_ / 64, B_ * KVH_), 256, 0, stream>>>(qkv, vT);
  flash<<<dim3(512), 512, 0, stream>>>(qn, kn, vT, ybf);
  gemm_bt<float><<<dim3(C_ / 128, M_ / 128), 256, 0, stream>>>(ybf, wprojb, out, C_, C_);
}